// Round 2
// baseline (747.285 us; speedup 1.0000x reference)
//
#include <hip/hip_runtime.h>

// Problem constants
#define BATCH 32
#define INCH 12
#define OUTCH 16
#define KSZ 5
#define H 384
#define W 384
#define OH 192
#define OW 192

// Workspace float offsets
#define WS_ACTSUM 0        // 512 floats  (b,oc) sums of activated
#define WS_POOLED 512      // 384 floats  (b,c) sums of x
#define WS_SCALE  896      // 512 floats  1 + gating
#define WS_RPROJ  1408     // 512 floats  res projection
#define WS_WT     1920     // 4800 floats transposed weight [300][16]

__global__ __launch_bounds__(256)
void init_ws(const float* __restrict__ weight, float* __restrict__ ws) {
    int t = threadIdx.x;
    for (int i = t; i < 896; i += 256) ws[i] = 0.f;
    float* wT = ws + WS_WT;
    for (int i = t; i < 4800; i += 256) {
        int oc = i / 300, k = i - oc * 300;
        wT[k * 16 + oc] = weight[i];
    }
}

// One block: 32x32 output tile, all 16 output channels.
// LDS holds one input-channel tile (67x67) de-interleaved by column parity
// so stride-2 reads are bank-conflict-free (2 lanes/bank).
__global__ __launch_bounds__(256)
void conv_act(const float* __restrict__ x,
              const float* __restrict__ wT,
              const float* __restrict__ bias,
              float* __restrict__ actsum,
              float* __restrict__ pooled,
              float* __restrict__ out) {
    __shared__ float lds[2][67][34];

    const int tile = blockIdx.x;           // 0..35
    const int b    = blockIdx.y;           // 0..31
    const int ty = tile / 6, tx = tile - ty * 6;
    const int oh0 = ty * 32, ow0 = tx * 32;
    const int ib_r = oh0 * 2 - 2;          // input tile base row (may be -2)
    const int ib_c = ow0 * 2 - 2;

    const int t  = threadIdx.x;
    const int cc = t & 31;                 // output col within tile
    const int r4 = t >> 5;                 // row group: rows r4*4 .. r4*4+3

    float acc[4][16];
#pragma unroll
    for (int m = 0; m < 4; ++m)
#pragma unroll
        for (int o = 0; o < 16; ++o) acc[m][o] = 0.f;

    for (int c = 0; c < INCH; ++c) {
        const float* xc = x + ((size_t)(b * INCH + c)) * (H * W);
        float psum = 0.f;
        for (int i = t; i < 67 * 67; i += 256) {
            int row = i / 67;
            int col = i - row * 67;
            int ih = ib_r + row, iw = ib_c + col;
            float v = 0.f;
            if ((unsigned)ih < (unsigned)H && (unsigned)iw < (unsigned)W)
                v = xc[ih * W + iw];
            lds[col & 1][row][col >> 1] = v;
            // exclusive 64x64 region (rel rows/cols 2..65) partitions the image
            if (row >= 2 && row <= 65 && col >= 2 && col <= 65) psum += v;
        }
        // wave-reduce psum -> pooled[b][c]
#pragma unroll
        for (int off = 32; off; off >>= 1) psum += __shfl_down(psum, off);
        if ((t & 63) == 0) atomicAdd(&pooled[b * INCH + c], psum);
        __syncthreads();

#pragma unroll
        for (int ky = 0; ky < 5; ++ky) {
#pragma unroll
            for (int kx = 0; kx < 5; ++kx) {
                const float* wp = wT + (c * 25 + ky * 5 + kx) * 16;
                float wv[16];
#pragma unroll
                for (int o = 0; o < 16; ++o) wv[o] = wp[o];
                const int p = kx & 1, a = kx >> 1;
#pragma unroll
                for (int m = 0; m < 4; ++m) {
                    float v = lds[p][8 * r4 + 2 * m + ky][cc + a];
#pragma unroll
                    for (int o = 0; o < 16; ++o)
                        acc[m][o] = fmaf(v, wv[o], acc[m][o]);
                }
            }
        }
        __syncthreads();
    }

    // bias + hardswish, store activated (fp32) to out, accumulate per-oc sums
    float osum[16];
#pragma unroll
    for (int o = 0; o < 16; ++o) osum[o] = 0.f;
#pragma unroll
    for (int m = 0; m < 4; ++m) {
        int r = r4 * 4 + m;
#pragma unroll
        for (int o = 0; o < 16; ++o) {
            float a = acc[m][o] + bias[o];
            float hs = a * fminf(fmaxf(a + 3.f, 0.f), 6.f) * (1.f / 6.f);
            out[(((size_t)b * OUTCH + o) * OH + (oh0 + r)) * OW + ow0 + cc] = hs;
            osum[o] += hs;
        }
    }
#pragma unroll
    for (int o = 0; o < 16; ++o) {
        float s = osum[o];
#pragma unroll
        for (int off = 32; off; off >>= 1) s += __shfl_down(s, off);
        if ((t & 63) == 0) atomicAdd(&actsum[b * OUTCH + o], s);
    }
}

__global__ __launch_bounds__(512)
void finalize(const float* __restrict__ actsum,
              const float* __restrict__ pooled,
              const float* __restrict__ res_w,
              float* __restrict__ scale,
              float* __restrict__ rproj) {
    int t = threadIdx.x;          // 512 = 32 b * 16 oc
    int b = t >> 4, oc = t & 15;
    float mean = actsum[t] * (1.f / (OH * OW));
    float g = fminf(fmaxf(mean, -0.5f), 0.5f);
    scale[t] = 1.f + g;
    float rp = 0.f;
#pragma unroll
    for (int c = 0; c < INCH; ++c)
        rp += pooled[b * INCH + c] * res_w[oc * INCH + c];
    rproj[t] = rp * (1.f / (H * W));
}

// One block per (b,oc) plane: out = clip(act*scale + rproj, +-0.5)
__global__ __launch_bounds__(256)
void epilogue(float* __restrict__ out,
              const float* __restrict__ scale,
              const float* __restrict__ rproj) {
    const int bo = blockIdx.x;            // 0..511
    const float s  = scale[bo];
    const float rp = rproj[bo];
    float4* p = reinterpret_cast<float4*>(out) + (size_t)bo * (OH * OW / 4);
    for (int i = threadIdx.x; i < OH * OW / 4; i += 256) {
        float4 v = p[i];
        v.x = fminf(fmaxf(fmaf(v.x, s, rp), -0.5f), 0.5f);
        v.y = fminf(fmaxf(fmaf(v.y, s, rp), -0.5f), 0.5f);
        v.z = fminf(fmaxf(fmaf(v.z, s, rp), -0.5f), 0.5f);
        v.w = fminf(fmaxf(fmaf(v.w, s, rp), -0.5f), 0.5f);
        p[i] = v;
    }
}

extern "C" void kernel_launch(void* const* d_in, const int* in_sizes, int n_in,
                              void* d_out, int out_size, void* d_ws, size_t ws_size,
                              hipStream_t stream) {
    const float* x      = (const float*)d_in[0];
    const float* weight = (const float*)d_in[1];
    const float* bias   = (const float*)d_in[2];
    const float* res_w  = (const float*)d_in[3];
    float* out = (float*)d_out;
    float* ws  = (float*)d_ws;

    init_ws<<<1, 256, 0, stream>>>(weight, ws);

    dim3 grid(36, 32);
    conv_act<<<grid, 256, 0, stream>>>(x, ws + WS_WT, bias,
                                       ws + WS_ACTSUM, ws + WS_POOLED, out);

    finalize<<<1, 512, 0, stream>>>(ws + WS_ACTSUM, ws + WS_POOLED, res_w,
                                    ws + WS_SCALE, ws + WS_RPROJ);

    epilogue<<<512, 256, 0, stream>>>(out, ws + WS_SCALE, ws + WS_RPROJ);
}